// Round 8
// baseline (2257.731 us; speedup 1.0000x reference)
//
#include <hip/hip_runtime.h>
#include <hip/hip_bf16.h>

#define Bz 32
#define Sz 240
#define Hz 1024
#define Lz 8
#define NHEADS 16
#define NVOCAB 48
#define DHEAD 64
#define VT_STRIDE 264

typedef unsigned short u16;
typedef unsigned int u32;
typedef __attribute__((ext_vector_type(8))) short short8v;
typedef __attribute__((ext_vector_type(4))) float floatx4;

__device__ __forceinline__ int get_len(const int* __restrict__ L, int b) {
  return (L[1] == 0) ? L[2 * b] : L[b];
}
__device__ __forceinline__ u16 f2bf(float f) {  // RNE fp32->bf16
  u32 u = __float_as_uint(f);
  return (u16)((u + 0x7FFFu + ((u >> 16) & 1u)) >> 16);
}
__device__ __forceinline__ float bf2f(u16 s) {
  return __uint_as_float(((u32)s) << 16);
}
__device__ __forceinline__ void async_copy16(const u16* g, u16* l) {
  __builtin_amdgcn_global_load_lds(
      (const __attribute__((address_space(1))) u32*)g,
      (__attribute__((address_space(3))) u32*)l, 16, 0, 0);
}

// ---------------- embedding ----------------
__global__ __launch_bounds__(256) void embed_kernel(
    const float* __restrict__ x, const float* __restrict__ w_emb,
    const float* __restrict__ p_emb, const int* __restrict__ lengths,
    float* __restrict__ z, u16* __restrict__ z_bf) {
  int bs = blockIdx.x;
  int b = bs / Sz, s = bs % Sz;
  __shared__ int stok;
  if (threadIdx.x == 0) {
    const float* xr = x + (size_t)bs * NVOCAB;
    float best = xr[0]; int bi = 0;
    for (int j = 1; j < NVOCAB; ++j) {
      float v = xr[j];
      if (v > best) { best = v; bi = j; }
    }
    stok = bi;
  }
  __syncthreads();
  int tok = stok;
  float valid = (s < get_len(lengths, b)) ? 1.f : 0.f;
  const float* we = w_emb + (size_t)tok * Hz;
  const float* pe = p_emb + (size_t)s * Hz;
  size_t base = (size_t)bs * Hz;
  for (int h = threadIdx.x; h < Hz; h += blockDim.x) {
    float v = we[h] * valid + pe[h];
    z[base + h] = v;
    z_bf[base + h] = f2bf(v);
  }
}

// ---------------- bias concat: [L][3072] = bq|bk|bv ----------------
__global__ __launch_bounds__(256) void bias_concat(
    const float* __restrict__ bq, const float* __restrict__ bk,
    const float* __restrict__ bv, float* __restrict__ dst) {
  int i = blockIdx.x * 256 + threadIdx.x;
  int l = i / 3072, c = i % 3072;
  float v = (c < 1024) ? bq[l * 1024 + c]
          : (c < 2048) ? bk[l * 1024 + c - 1024]
                       : bv[l * 1024 + c - 2048];
  dst[i] = v;
}

// ---------------- weight convert+transpose, 5 matrices per layer ----------------
struct WconvArgs { const float* src[5]; u16* dst[5]; };
__global__ __launch_bounds__(256) void wconv5(WconvArgs a) {
  __shared__ u16 T[32][33];
  const float* W = a.src[blockIdx.z];
  u16* wt = a.dst[blockIdx.z];
  int bi = blockIdx.y, bj = blockIdx.x;
  int r = threadIdx.x >> 3, c4 = (threadIdx.x & 7) * 4;
  float4 w4 = *(const float4*)(W + (size_t)(bi * 32 + r) * Hz + bj * 32 + c4);
  T[r][c4 + 0] = f2bf(w4.x); T[r][c4 + 1] = f2bf(w4.y);
  T[r][c4 + 2] = f2bf(w4.z); T[r][c4 + 3] = f2bf(w4.w);
  __syncthreads();
  u32 lo = (u32)T[c4 + 0][r] | ((u32)T[c4 + 1][r] << 16);
  u32 hi = (u32)T[c4 + 2][r] | ((u32)T[c4 + 3][r] << 16);
  uint2 val; val.x = lo; val.y = hi;
  *(uint2*)(wt + (size_t)(bj * 32 + r) * Hz + bi * 32 + c4) = val;
}

// ---------------- MFMA GEMM, 256xBN tile, counted-vmcnt pipeline (round-6) ----
// C[7680,nco] = A(bf16)[7680,1024] @ Wt[nco,1024]^T + bias (+resid)
// Verified best (round 6, QKV 97us). Raw s_barrier + counted s_waitcnt vmcnt(N)
// (never 0 in steady state) so prefetched global_load_lds stay in flight
// ACROSS barriers. Per iter: ds_read all frags -> lgkmcnt(0)+sched_barrier ->
// s_barrier (WAR) -> restage buf[cur] for k+2 -> setprio(1) MFMAs setprio(0)
// -> counted vmcnt -> s_barrier. Buffer written at iter t is read at t+2;
// iter t+1's vmcnt+barrier publishes it. All branches wave-uniform.
template <int BN, bool OUTBF16, bool GELU, bool RESID>
__global__ __launch_bounds__(512, 2) void gemm_mfma(
    const u16* __restrict__ A, const u16* __restrict__ Wt,
    const float* __restrict__ bias, const float* __restrict__ resid,
    void* __restrict__ Cv, int nco) {
  constexpr int MT = (BN == 256) ? 8 : 4;   // 16-row fragments per wave
  constexpr int WGC = (BN == 256) ? 4 : 2;  // waves along N
  constexpr int BKT = BN * 32;              // Bs elems per ktile(32k)
  __shared__ u16 As[2][16384];              // [buf][kt(2)][rowblk(16)][512]
  __shared__ u16 Bs[2][BN * 64];
  int tid = threadIdx.x;
  int nwg = (int)gridDim.x;
  int id0 = blockIdx.x;
  int id = (id0 & 7) * (nwg >> 3) + (id0 >> 3);   // bijective: nwg % 8 == 0
  int ncols = nco / BN;
  int row0 = (id / ncols) * 256;
  int col0 = (id % ncols) * BN;

  int w = tid >> 6, lane = tid & 63;
  int l15 = lane & 15, lq = lane >> 4;
  int wr = w / WGC, wc = w % WGC;
  floatx4 acc[MT][4] = {};

  const u16* gA0 = A + (size_t)(row0 + 32 * w + l15) * 1024 + 8 * lq;
  const u16* gA1 = gA0 + 16 * 1024;
  const u16* gB0 = Wt + (size_t)(col0 + (BN == 256 ? 32 : 16) * w + l15) * 1024 + 8 * lq;
  const u16* gB1 = gB0 + 16 * 1024;  // unused for BN==128

  auto stage = [&](int bb, int kk) {
#pragma unroll
    for (int kt = 0; kt < 2; ++kt) {
      async_copy16(gA0 + kk + 32 * kt, &As[bb][kt * 8192 + (2 * w) * 512]);
      async_copy16(gA1 + kk + 32 * kt, &As[bb][kt * 8192 + (2 * w + 1) * 512]);
      if constexpr (BN == 256) {
        async_copy16(gB0 + kk + 32 * kt, &Bs[bb][kt * BKT + (2 * w) * 512]);
        async_copy16(gB1 + kk + 32 * kt, &Bs[bb][kt * BKT + (2 * w + 1) * 512]);
      } else {
        async_copy16(gB0 + kk + 32 * kt, &Bs[bb][kt * BKT + w * 512]);
      }
    }
  };

  int afrag_off[MT], bfrag_off[4];
#pragma unroll
  for (int i = 0; i < MT; ++i)
    afrag_off[i] = (wr * MT + i) * 512 + lq * 128 + l15 * 8;
#pragma unroll
  for (int j = 0; j < 4; ++j)
    bfrag_off[j] = (wc * 4 + j) * 512 + lq * 128 + l15 * 8;

#define WAIT_VM_N()                                                  \
  do {                                                               \
    if constexpr (BN == 256)                                         \
      __asm__ volatile("s_waitcnt vmcnt(8)" ::: "memory");           \
    else                                                             \
      __asm__ volatile("s_waitcnt vmcnt(6)" ::: "memory");           \
  } while (0)

  // prologue: two batches in flight; confirm batch 0 only (counted wait).
  stage(0, 0);
  stage(1, 64);
  WAIT_VM_N();
  __builtin_amdgcn_s_barrier();
  __builtin_amdgcn_sched_barrier(0);

  int cur = 0;
  for (int k0 = 0; k0 < 1024; k0 += 64) {
    // 1. LDS -> regs for buf[cur]
    short8v af0[MT], bf0[4], af1[MT], bf1[4];
#pragma unroll
    for (int i = 0; i < MT; ++i) {
      af0[i] = *(const short8v*)(&As[cur][afrag_off[i]]);
      af1[i] = *(const short8v*)(&As[cur][8192 + afrag_off[i]]);
    }
#pragma unroll
    for (int j = 0; j < 4; ++j) {
      bf0[j] = *(const short8v*)(&Bs[cur][bfrag_off[j]]);
      bf1[j] = *(const short8v*)(&Bs[cur][BKT + bfrag_off[j]]);
    }
    __asm__ volatile("s_waitcnt lgkmcnt(0)" ::: "memory");
    __builtin_amdgcn_sched_barrier(0);
    // 2. WAR barrier: every wave's reads are in registers
    __builtin_amdgcn_s_barrier();
    __builtin_amdgcn_sched_barrier(0);
    // 3. restage this buffer for k0+128 (uniform branch)
    if (k0 + 128 < 1024) stage(cur, k0 + 128);
    // 4. MFMA cluster
    __builtin_amdgcn_s_setprio(1);
#pragma unroll
    for (int mi = 0; mi < MT; ++mi)
#pragma unroll
      for (int ni = 0; ni < 4; ++ni)
        acc[mi][ni] = __builtin_amdgcn_mfma_f32_16x16x32_bf16(
            af0[mi], bf0[ni], acc[mi][ni], 0, 0, 0);
#pragma unroll
    for (int mi = 0; mi < MT; ++mi)
#pragma unroll
      for (int ni = 0; ni < 4; ++ni)
        acc[mi][ni] = __builtin_amdgcn_mfma_f32_16x16x32_bf16(
            af1[mi], bf1[ni], acc[mi][ni], 0, 0, 0);
    __builtin_amdgcn_s_setprio(0);
    // 5. publish prev iter's batch (counted; 0 only at tail), then barrier
    if (k0 + 64 < 1024) {
      if (k0 + 128 < 1024) {
        WAIT_VM_N();
      } else {
        __asm__ volatile("s_waitcnt vmcnt(0)" ::: "memory");
      }
      __builtin_amdgcn_s_barrier();
      __builtin_amdgcn_sched_barrier(0);
    }
    cur ^= 1;
  }
#undef WAIT_VM_N

  int rowbase = row0 + wr * (MT * 16), colbase = col0 + wc * 64;
#pragma unroll
  for (int ni = 0; ni < 4; ++ni) {
    int col = colbase + ni * 16 + l15;
    float bcol = bias[col];
#pragma unroll
    for (int mi = 0; mi < MT; ++mi) {
      int rtop = rowbase + mi * 16 + lq * 4;
#pragma unroll
      for (int reg = 0; reg < 4; ++reg) {
        float vv = acc[mi][ni][reg] + bcol;
        if (RESID) vv += resid[(size_t)(rtop + reg) * nco + col];
        if (GELU) vv = 0.5f * vv * (1.f + erff(vv * 0.70710678118654752f));
        if (OUTBF16)
          ((u16*)Cv)[(size_t)(rtop + reg) * nco + col] = f2bf(vv);
        else
          ((float*)Cv)[(size_t)(rtop + reg) * nco + col] = vv;
      }
    }
  }
}

// ---------------- MFMA flash attention (packed qkv, stride 3072); out = z + attn ------
// Round-8 changes: (1) K staged once into LDS (30 KB, MFMA-B-frag layout via
// linear global_load_lds) -> inner loop reads K via ds_read_b128 instead of
// 6KB-strided global loads (removes HBM/L2 latency from the per-step chain).
// (2) Vt transpose XOR-swizzled: key' = key ^ (((row>>2)&7)<<3), write+read
// matched, 16B-aligned -> 8-way bank conflict becomes ~2-way (free).
// LDS 69.6 KB -> 2 blocks/CU (was 4).
__global__ __launch_bounds__(256) void attention_kernel(
    const u16* __restrict__ qkv, const int* __restrict__ lengths,
    const float* __restrict__ zres, float* __restrict__ out) {
  const int LDQ = 3072;
  __shared__ u16 Vt[64 * VT_STRIDE];
  __shared__ u16 Kl[30 * 512];   // [t*2+dh][lq*128 + l15*8]
  __shared__ u16 Pb[4][16 * 40];
  int hh = blockIdx.x & 1;
  int h = (blockIdx.x >> 1) & 15;
  int b = blockIdx.x >> 5;
  int tid = threadIdx.x;
  const size_t base = ((size_t)b * Sz) * LDQ + (size_t)h * DHEAD;
  const u16* qp = qkv + base;
  const u16* kp = qkv + base + 1024;
  const u16* vp = qkv + base + 2048;

  int w = tid >> 6, lane = tid & 63;
  int qgroup = lane >> 4, qcol = lane & 15;

  // stage K: 30 units of 16 rows x 32 d; linear LDS dest == frag layout since
  // lane*8 == (lane>>4)*128 + (lane&15)*8. Max row = 14*16+15 = 239 (in bounds).
  for (int u = w; u < 30; u += 4) {
    int t = u >> 1, dh = u & 1;
    async_copy16(kp + (size_t)(t * 16 + qcol) * LDQ + dh * 32 + qgroup * 8,
                 &Kl[u * 512]);
  }

  // V transpose with XOR key-block swizzle (selector m = d4>>2, same for j=0..3)
  for (int idx = tid; idx < 256 * 16; idx += 256) {
    int key = idx >> 4, m = idx & 15, d4 = m * 4;
    uint2 vv;
    if (key < Sz) vv = *(const uint2*)(vp + (size_t)key * LDQ + d4);
    else { vv.x = 0u; vv.y = 0u; }
    int keysw = key ^ ((m & 7) << 3);
    Vt[(d4 + 0) * VT_STRIDE + keysw] = (u16)(vv.x & 0xFFFF);
    Vt[(d4 + 1) * VT_STRIDE + keysw] = (u16)(vv.x >> 16);
    Vt[(d4 + 2) * VT_STRIDE + keysw] = (u16)(vv.y & 0xFFFF);
    Vt[(d4 + 3) * VT_STRIDE + keysw] = (u16)(vv.y >> 16);
  }
  __syncthreads();   // drains vmcnt (K staged) + lgkm (V writes)

  int len_b = get_len(lengths, b);

  for (int qt = hh * 8 + w; qt < hh * 8 + 8 && qt < 15; qt += 4) {
    const u16* qrow = qp + (size_t)(qt * 16 + qcol) * LDQ;
    short8v aq0 = *(const short8v*)(qrow + qgroup * 8);
    short8v aq1 = *(const short8v*)(qrow + 32 + qgroup * 8);
    floatx4 o0 = {0.f, 0.f, 0.f, 0.f}, o1 = o0, o2 = o0, o3 = o0;
    float m_run[4] = {-1e30f, -1e30f, -1e30f, -1e30f};
    float l_run[4] = {0.f, 0.f, 0.f, 0.f};
    int nsteps = (qt + 2) >> 1;

    for (int st = 0; st < nsteps; ++st) {
      int t0 = 2 * st, t1 = 2 * st + 1;
      bool has1 = (t1 <= qt);
      int koff = qgroup * 128 + qcol * 8;
      floatx4 s0 = {0.f, 0.f, 0.f, 0.f};
      {
        short8v bk0 = *(const short8v*)(&Kl[(t0 * 2 + 0) * 512 + koff]);
        short8v bk1 = *(const short8v*)(&Kl[(t0 * 2 + 1) * 512 + koff]);
        s0 = __builtin_amdgcn_mfma_f32_16x16x32_bf16(aq0, bk0, s0, 0, 0, 0);
        s0 = __builtin_amdgcn_mfma_f32_16x16x32_bf16(aq1, bk1, s0, 0, 0, 0);
      }
      floatx4 s1 = {0.f, 0.f, 0.f, 0.f};
      if (has1) {
        short8v bk0 = *(const short8v*)(&Kl[(t1 * 2 + 0) * 512 + koff]);
        short8v bk1 = *(const short8v*)(&Kl[(t1 * 2 + 1) * 512 + koff]);
        s1 = __builtin_amdgcn_mfma_f32_16x16x32_bf16(aq0, bk0, s1, 0, 0, 0);
        s1 = __builtin_amdgcn_mfma_f32_16x16x32_bf16(aq1, bk1, s1, 0, 0, 0);
      }
      int kg0 = t0 * 16 + qcol, kg1 = t1 * 16 + qcol;
      float p0[4], p1[4];
#pragma unroll
      for (int rg = 0; rg < 4; ++rg) {
        int row_g = qt * 16 + qgroup * 4 + rg;
        float x0 = (kg0 <= row_g) ? s0[rg] * 0.03125f : -1e30f;
        float x1 = (has1 && kg1 <= row_g) ? s1[rg] * 0.03125f : -1e30f;
        float mx = fmaxf(x0, x1);
        mx = fmaxf(mx, __shfl_xor(mx, 1));
        mx = fmaxf(mx, __shfl_xor(mx, 2));
        mx = fmaxf(mx, __shfl_xor(mx, 4));
        mx = fmaxf(mx, __shfl_xor(mx, 8));
        float mnew = fmaxf(m_run[rg], mx);
        float alpha = __expf(m_run[rg] - mnew);
        float e0 = __expf(x0 - mnew);
        float e1 = __expf(x1 - mnew);
        float rs = e0 + e1;
        rs += __shfl_xor(rs, 1);
        rs += __shfl_xor(rs, 2);
        rs += __shfl_xor(rs, 4);
        rs += __shfl_xor(rs, 8);
        l_run[rg] = l_run[rg] * alpha + rs;
        m_run[rg] = mnew;
        o0[rg] *= alpha; o1[rg] *= alpha; o2[rg] *= alpha; o3[rg] *= alpha;
        p0[rg] = e0; p1[rg] = e1;
      }
#pragma unroll
      for (int rg = 0; rg < 4; ++rg) {
        int rl = qgroup * 4 + rg;
        Pb[w][rl * 40 + qcol] = f2bf(p0[rg]);
        Pb[w][rl * 40 + 16 + qcol] = f2bf(p1[rg]);
      }
      __asm__ volatile("s_waitcnt lgkmcnt(0)" ::: "memory");
      short8v pa = *(const short8v*)(&Pb[w][qcol * 40 + qgroup * 8]);
      // V reads: row = dblk*16 + qcol, swizzled key block
      int kbix = st * 4 + qgroup;   // 8-key block index
#pragma unroll
      for (int dblk = 0; dblk < 1; ++dblk) {}   // (kept structure explicit below)
      int r0 = 0 * 16 + qcol, r1 = 1 * 16 + qcol, r2 = 2 * 16 + qcol, r3 = 3 * 16 + qcol;
      short8v bv0 = *(const short8v*)(&Vt[r0 * VT_STRIDE + ((kbix ^ ((r0 >> 2) & 7)) << 3)]);
      short8v bv1 = *(const short8v*)(&Vt[r1 * VT_STRIDE + ((kbix ^ ((r1 >> 2) & 7)) << 3)]);
      short8v bv2 = *(const short8v*)(&Vt[r2 * VT_STRIDE + ((kbix ^ ((r2 >> 2) & 7)) << 3)]);
      short8v bv3 = *(const short8v*)(&Vt[r3 * VT_STRIDE + ((kbix ^ ((r3 >> 2) & 7)) << 3)]);
      o0 = __builtin_amdgcn_mfma_f32_16x16x32_bf16(pa, bv0, o0, 0, 0, 0);
      o1 = __builtin_amdgcn_mfma_f32_16x16x32_bf16(pa, bv1, o1, 0, 0, 0);
      o2 = __builtin_amdgcn_mfma_f32_16x16x32_bf16(pa, bv2, o2, 0, 0, 0);
      o3 = __builtin_amdgcn_mfma_f32_16x16x32_bf16(pa, bv3, o3, 0, 0, 0);
    }

#pragma unroll
    for (int rg = 0; rg < 4; ++rg) {
      int row_g = qt * 16 + qgroup * 4 + rg;
      float vmask = (row_g < len_b) ? (1.f / l_run[rg]) : 0.f;
      size_t ob = ((size_t)b * Sz + row_g) * Hz + (size_t)h * DHEAD + qcol;
      out[ob]      = zres[ob]      + o0[rg] * vmask;
      out[ob + 16] = zres[ob + 16] + o1[rg] * vmask;
      out[ob + 32] = zres[ob + 32] + o2[rg] * vmask;
      out[ob + 48] = zres[ob + 48] + o3[rg] * vmask;
    }
  }
}

// ---------------- LayerNorm of r (residual pre-added); writes z, z_bf ----------------
__global__ __launch_bounds__(256) void add_ln_kernel(
    float* __restrict__ z, u16* __restrict__ z_bf, const float* __restrict__ r,
    const float* __restrict__ gamma, const float* __restrict__ beta) {
  int bs = blockIdx.x, tid = threadIdx.x;
  size_t base = (size_t)bs * Hz;
  __shared__ float sred[256];
  float4 v4 = *(const float4*)(r + base + tid * 4);
  float sum = v4.x + v4.y + v4.z + v4.w;
  sred[tid] = sum; __syncthreads();
  for (int off = 128; off > 0; off >>= 1) {
    if (tid < off) sred[tid] += sred[tid + off];
    __syncthreads();
  }
  float mean = sred[0] * (1.f / Hz); __syncthreads();
  float dx = v4.x - mean, dy = v4.y - mean, dz = v4.z - mean, dw = v4.w - mean;
  sred[tid] = dx * dx + dy * dy + dz * dz + dw * dw; __syncthreads();
  for (int off = 128; off > 0; off >>= 1) {
    if (tid < off) sred[tid] += sred[tid + off];
    __syncthreads();
  }
  float rstd = rsqrtf(sred[0] * (1.f / Hz) + 1e-5f);
  float4 g4 = *(const float4*)(gamma + tid * 4);
  float4 b4 = *(const float4*)(beta + tid * 4);
  float4 o;
  o.x = dx * rstd * g4.x + b4.x;
  o.y = dy * rstd * g4.y + b4.y;
  o.z = dz * rstd * g4.z + b4.z;
  o.w = dw * rstd * g4.w + b4.w;
  *(float4*)(z + base + tid * 4) = o;
  uint2 pk;
  pk.x = (u32)f2bf(o.x) | ((u32)f2bf(o.y) << 16);
  pk.y = (u32)f2bf(o.z) | ((u32)f2bf(o.w) << 16);
  *(uint2*)(z_bf + base + tid * 4) = pk;
}

// ---------------- pool phase 1 ----------------
__global__ __launch_bounds__(256) void pool1_kernel(
    const float* __restrict__ z, float* __restrict__ pooled) {
  int chunk = blockIdx.x, b = blockIdx.y, tid = threadIdx.x;
  int h = chunk * 128 + (tid & 127);
  int half = tid >> 7;
  __shared__ float sred[256];
  const float* zp = z + ((size_t)b * Sz + half * 120) * Hz + h;
  float s = 0.f;
  for (int i = 0; i < 120; ++i) s += zp[(size_t)i * Hz];
  sred[tid] = s; __syncthreads();
  if (tid < 128)
    pooled[(size_t)b * Hz + chunk * 128 + tid] =
        (sred[tid] + sred[tid + 128]) * (1.f / Sz);
}

// ---------------- pool phase 2: FC + softmax -> fp32 out ----------------
__global__ __launch_bounds__(256) void pool2_kernel(
    const float* __restrict__ pooled, const float* __restrict__ Wfc,
    const float* __restrict__ bfc, float* __restrict__ out) {
  int b = blockIdx.x, tid = threadIdx.x;
  __shared__ float red[256][4];
  float acc[4] = {0.f, 0.f, 0.f, 0.f};
#pragma unroll
  for (int j = 0; j < 4; ++j) {
    int hh = tid * 4 + j;
    float z2 = pooled[(size_t)b * Hz + hh];
#pragma unroll
    for (int c = 0; c < 4; ++c) acc[c] += z2 * Wfc[hh * 4 + c];
  }
#pragma unroll
  for (int c = 0; c < 4; ++c) red[tid][c] = acc[c];
  __syncthreads();
  for (int off = 128; off > 0; off >>= 1) {
    if (tid < off)
#pragma unroll
      for (int c = 0; c < 4; ++c) red[tid][c] += red[tid + off][c];
    __syncthreads();
  }
  if (tid == 0) {
    float lg[4], m = -1e30f;
#pragma unroll
    for (int c = 0; c < 4; ++c) { lg[c] = red[0][c] + bfc[c]; m = fmaxf(m, lg[c]); }
    float s = 0.f;
#pragma unroll
    for (int c = 0; c < 4; ++c) { lg[c] = expf(lg[c] - m); s += lg[c]; }
    float inv = 1.f / s;
#pragma unroll
    for (int c = 0; c < 4; ++c) out[b * 4 + c] = lg[c] * inv;
  }
}

extern "C" void kernel_launch(void* const* d_in, const int* in_sizes, int n_in,
                              void* d_out, int out_size, void* d_ws, size_t ws_size,
                              hipStream_t stream) {
  const float* x     = (const float*)d_in[0];
  const float* w_emb = (const float*)d_in[1];
  const float* p_emb = (const float*)d_in[2];
  const float* Wq = (const float*)d_in[3];
  const float* bq = (const float*)d_in[4];
  const float* Wk = (const float*)d_in[5];
  const float* bk = (const float*)d_in[6];
  const float* Wv = (const float*)d_in[7];
  const float* bv = (const float*)d_in[8];
  const float* W1 = (const float*)d_in[9];
  const float* b1 = (const float*)d_in[10];
  const float* W2 = (const float*)d_in[11];
  const float* b2 = (const float*)d_in[12];
  const float* ln1s = (const float*)d_in[13];
  const float* ln1b = (const float*)d_in[14];
  const float* ln2s = (const float*)d_in[15];
  const float* ln2b = (const float*)d_in[16];
  const float* Wfc  = (const float*)d_in[17];
  const float* bfc  = (const float*)d_in[18];
  const int* lengths = (const int*)d_in[19];
  float* out = (float*)d_out;

  const size_t BSH = (size_t)Bz * Sz * Hz;   // 7,864,320
  float* z    = (float*)d_ws;                // fp32 BSH
  float* ao   = z + BSH;                     // fp32 BSH (z+attn / z1+ff2)
  u16* z_bf   = (u16*)(ao + BSH);            // bf16 BSH
  u16* ffb    = z_bf + BSH;                  // bf16 BSH (FF1 out)
  u16* qkv    = ffb + BSH;                   // bf16 3*BSH
  u16* wt     = qkv + 3 * BSH;               // bf16 5M
  float* bqkv = (float*)(wt + 5 * 1024 * 1024);   // Lz*3072
  float* pooled = bqkv + Lz * 3072;          // 32*1024 fp32

  embed_kernel<<<Bz * Sz, 256, 0, stream>>>(x, w_emb, p_emb, lengths, z, z_bf);
  bias_concat<<<Lz * 3072 / 256, 256, 0, stream>>>(bq, bk, bv, bqkv);

  for (int i = 0; i < Lz; ++i) {
    size_t wo = (size_t)i * Hz * Hz, bo = (size_t)i * Hz;
    WconvArgs wa;
    wa.src[0] = Wq + wo; wa.src[1] = Wk + wo; wa.src[2] = Wv + wo;
    wa.src[3] = W1 + wo; wa.src[4] = W2 + wo;
    wa.dst[0] = wt;                     wa.dst[1] = wt + 1024 * 1024;
    wa.dst[2] = wt + 2 * 1024 * 1024;   wa.dst[3] = wt + 3 * 1024 * 1024;
    wa.dst[4] = wt + 4 * 1024 * 1024;
    wconv5<<<dim3(32, 32, 5), 256, 0, stream>>>(wa);

    gemm_mfma<256, true, false, false><<<30 * 12, 512, 0, stream>>>(
        z_bf, wt, bqkv + (size_t)i * 3072, nullptr, qkv, 3072);
    attention_kernel<<<Bz * NHEADS * 2, 256, 0, stream>>>(qkv, lengths, z, ao);
    add_ln_kernel<<<Bz * Sz, 256, 0, stream>>>(z, z_bf, ao, ln1s + bo, ln1b + bo);
    gemm_mfma<128, true, true, false><<<30 * 8, 512, 0, stream>>>(
        z_bf, wt + 3 * 1024 * 1024, b1 + bo, nullptr, ffb, 1024);
    gemm_mfma<128, false, false, true><<<30 * 8, 512, 0, stream>>>(
        ffb, wt + 4 * 1024 * 1024, b2 + bo, z, ao, 1024);
    add_ln_kernel<<<Bz * Sz, 256, 0, stream>>>(z, z_bf, ao, ln2s + bo, ln2b + bo);
  }
  pool1_kernel<<<dim3(8, Bz), 256, 0, stream>>>(z, pooled);
  pool2_kernel<<<Bz, 256, 0, stream>>>(pooled, Wfc, bfc, out);
}

// Round 9
// 1984.268 us; speedup vs baseline: 1.1378x; 1.1378x over previous
//
#include <hip/hip_runtime.h>
#include <hip/hip_bf16.h>

#define Bz 32
#define Sz 240
#define Hz 1024
#define Lz 8
#define NHEADS 16
#define NVOCAB 48
#define DHEAD 64
#define VT_STRIDE 264

typedef unsigned short u16;
typedef unsigned int u32;
typedef __attribute__((ext_vector_type(8))) short short8v;
typedef __attribute__((ext_vector_type(4))) float floatx4;

__device__ __forceinline__ int get_len(const int* __restrict__ L, int b) {
  return (L[1] == 0) ? L[2 * b] : L[b];
}
__device__ __forceinline__ u16 f2bf(float f) {  // RNE fp32->bf16
  u32 u = __float_as_uint(f);
  return (u16)((u + 0x7FFFu + ((u >> 16) & 1u)) >> 16);
}
__device__ __forceinline__ float bf2f(u16 s) {
  return __uint_as_float(((u32)s) << 16);
}
__device__ __forceinline__ void async_copy16(const u16* g, u16* l) {
  __builtin_amdgcn_global_load_lds(
      (const __attribute__((address_space(1))) u32*)g,
      (__attribute__((address_space(3))) u32*)l, 16, 0, 0);
}

// ---------------- embedding ----------------
__global__ __launch_bounds__(256) void embed_kernel(
    const float* __restrict__ x, const float* __restrict__ w_emb,
    const float* __restrict__ p_emb, const int* __restrict__ lengths,
    float* __restrict__ z, u16* __restrict__ z_bf) {
  int bs = blockIdx.x;
  int b = bs / Sz, s = bs % Sz;
  __shared__ int stok;
  if (threadIdx.x == 0) {
    const float* xr = x + (size_t)bs * NVOCAB;
    float best = xr[0]; int bi = 0;
    for (int j = 1; j < NVOCAB; ++j) {
      float v = xr[j];
      if (v > best) { best = v; bi = j; }
    }
    stok = bi;
  }
  __syncthreads();
  int tok = stok;
  float valid = (s < get_len(lengths, b)) ? 1.f : 0.f;
  const float* we = w_emb + (size_t)tok * Hz;
  const float* pe = p_emb + (size_t)s * Hz;
  size_t base = (size_t)bs * Hz;
  for (int h = threadIdx.x; h < Hz; h += blockDim.x) {
    float v = we[h] * valid + pe[h];
    z[base + h] = v;
    z_bf[base + h] = f2bf(v);
  }
}

// ---------------- bias concat: [L][3072] = bq|bk|bv ----------------
__global__ __launch_bounds__(256) void bias_concat(
    const float* __restrict__ bq, const float* __restrict__ bk,
    const float* __restrict__ bv, float* __restrict__ dst) {
  int i = blockIdx.x * 256 + threadIdx.x;
  int l = i / 3072, c = i % 3072;
  float v = (c < 1024) ? bq[l * 1024 + c]
          : (c < 2048) ? bk[l * 1024 + c - 1024]
                       : bv[l * 1024 + c - 2048];
  dst[i] = v;
}

// ---------------- weight convert+transpose, 5 matrices per layer ----------------
struct WconvArgs { const float* src[5]; u16* dst[5]; };
__global__ __launch_bounds__(256) void wconv5(WconvArgs a) {
  __shared__ u16 T[32][33];
  const float* W = a.src[blockIdx.z];
  u16* wt = a.dst[blockIdx.z];
  int bi = blockIdx.y, bj = blockIdx.x;
  int r = threadIdx.x >> 3, c4 = (threadIdx.x & 7) * 4;
  float4 w4 = *(const float4*)(W + (size_t)(bi * 32 + r) * Hz + bj * 32 + c4);
  T[r][c4 + 0] = f2bf(w4.x); T[r][c4 + 1] = f2bf(w4.y);
  T[r][c4 + 2] = f2bf(w4.z); T[r][c4 + 3] = f2bf(w4.w);
  __syncthreads();
  u32 lo = (u32)T[c4 + 0][r] | ((u32)T[c4 + 1][r] << 16);
  u32 hi = (u32)T[c4 + 2][r] | ((u32)T[c4 + 3][r] << 16);
  uint2 val; val.x = lo; val.y = hi;
  *(uint2*)(wt + (size_t)(bj * 32 + r) * Hz + bi * 32 + c4) = val;
}

// ---------------- MFMA GEMM, 256xBN tile, 2-phase-per-K-tile counted pipeline --
// C[7680,nco] = A(bf16)[7680,1024] @ Wt[nco,1024]^T + bias (+resid)
// r6 ledger refined: each K-tile (BK=64) is two phases (k-halves). Phase =
//   { 12 ds_read(kh of buf[cur]) ; stage kh of K-tile i+1 -> buf[cur^1] ;
//     s_barrier ; lgkmcnt(0) ; setprio(1) 32 MFMA setprio(0) ;
//     vmcnt(LPH) ; s_barrier }
// Counted vmcnt(LPH) at EVERY phase boundary (never 0 until the tail):
// allows only the newest half-stage to fly; the half staged one iteration
// ago (needed by the matching phase of the next iteration) is confirmed.
// Collective via the trailing barrier (per-wave own-load vmcnt + barrier).
// WAR: buf[cur^1] last read at iter i-1; those reads completed before that
// iter's trailing barriers, which precede this iter's stage issuance.
// All branches wave-uniform; k-ascending (kh0 then kh1): bit-identical.
template <int BN, bool OUTBF16, bool GELU, bool RESID>
__global__ __launch_bounds__(512, 2) void gemm_mfma(
    const u16* __restrict__ A, const u16* __restrict__ Wt,
    const float* __restrict__ bias, const float* __restrict__ resid,
    void* __restrict__ Cv, int nco) {
  constexpr int MT = (BN == 256) ? 8 : 4;   // 16-row fragments per wave
  constexpr int WGC = (BN == 256) ? 4 : 2;  // waves along N
  constexpr int BS_KH = BN * 32;            // Bs elems per k-half
  __shared__ u16 As[2][16384];              // [buf][kh(2)][rowblk(16)][512]
  __shared__ u16 Bs[2][BN * 64];
  int tid = threadIdx.x;
  int nwg = (int)gridDim.x;
  int id0 = blockIdx.x;
  int id = (id0 & 7) * (nwg >> 3) + (id0 >> 3);   // bijective: nwg % 8 == 0
  int ncols = nco / BN;
  int row0 = (id / ncols) * 256;
  int col0 = (id % ncols) * BN;

  int w = tid >> 6, lane = tid & 63;
  int l15 = lane & 15, lq = lane >> 4;
  int wr = w / WGC, wc = w % WGC;
  floatx4 acc[MT][4] = {};

  const u16* gA0 = A + (size_t)(row0 + 32 * w + l15) * 1024 + 8 * lq;
  const u16* gA1 = gA0 + 16 * 1024;
  const u16* gB0 = Wt + (size_t)(col0 + (BN == 256 ? 32 : 16) * w + l15) * 1024 + 8 * lq;
  const u16* gB1 = gB0 + 16 * 1024;  // unused for BN==128

  // stage one k-half (kt in {0,1}) of the K-tile at offset kk into buf bb
  auto stage_h = [&](int bb, int kk, int kt) {
    async_copy16(gA0 + kk + 32 * kt, &As[bb][kt * 8192 + (2 * w) * 512]);
    async_copy16(gA1 + kk + 32 * kt, &As[bb][kt * 8192 + (2 * w + 1) * 512]);
    if constexpr (BN == 256) {
      async_copy16(gB0 + kk + 32 * kt, &Bs[bb][kt * BS_KH + (2 * w) * 512]);
      async_copy16(gB1 + kk + 32 * kt, &Bs[bb][kt * BS_KH + (2 * w + 1) * 512]);
    } else {
      async_copy16(gB0 + kk + 32 * kt, &Bs[bb][kt * BS_KH + w * 512]);
    }
  };

  int afrag_off[MT], bfrag_off[4];
#pragma unroll
  for (int i = 0; i < MT; ++i)
    afrag_off[i] = (wr * MT + i) * 512 + lq * 128 + l15 * 8;
#pragma unroll
  for (int j = 0; j < 4; ++j)
    bfrag_off[j] = (wc * 4 + j) * 512 + lq * 128 + l15 * 8;

#define WAIT_VM_H()                                                  \
  do {                                                               \
    if constexpr (BN == 256)                                         \
      __asm__ volatile("s_waitcnt vmcnt(4)" ::: "memory");           \
    else                                                             \
      __asm__ volatile("s_waitcnt vmcnt(3)" ::: "memory");           \
  } while (0)

  // prologue: K-tile 0 fully staged; confirm kh0 only (kh1 may fly).
  stage_h(0, 0, 0);
  stage_h(0, 0, 1);
  WAIT_VM_H();
  __builtin_amdgcn_s_barrier();
  __builtin_amdgcn_sched_barrier(0);

  int cur = 0;
  for (int i = 0; i < 16; ++i) {
    int kks = (i + 1) << 6;       // next K-tile's global k offset
    bool st = (i < 15);           // uniform
    short8v af[MT], bf[4];

    // ---- phase 0 : k-half 0 ----
#pragma unroll
    for (int m = 0; m < MT; ++m)
      af[m] = *(const short8v*)(&As[cur][afrag_off[m]]);
#pragma unroll
    for (int n = 0; n < 4; ++n)
      bf[n] = *(const short8v*)(&Bs[cur][bfrag_off[n]]);
    if (st) stage_h(cur ^ 1, kks, 0);
    __builtin_amdgcn_s_barrier();
    __asm__ volatile("s_waitcnt lgkmcnt(0)" ::: "memory");
    __builtin_amdgcn_sched_barrier(0);
    __builtin_amdgcn_s_setprio(1);
#pragma unroll
    for (int mi = 0; mi < MT; ++mi)
#pragma unroll
      for (int ni = 0; ni < 4; ++ni)
        acc[mi][ni] = __builtin_amdgcn_mfma_f32_16x16x32_bf16(
            af[mi], bf[ni], acc[mi][ni], 0, 0, 0);
    __builtin_amdgcn_s_setprio(0);
    if (st) {
      WAIT_VM_H();                 // prev iter's kh1 landed; this kh0 flies
    } else {
      __asm__ volatile("s_waitcnt vmcnt(0)" ::: "memory");  // tail: kh1 of K15
    }
    __builtin_amdgcn_s_barrier();
    __builtin_amdgcn_sched_barrier(0);

    // ---- phase 1 : k-half 1 ----
#pragma unroll
    for (int m = 0; m < MT; ++m)
      af[m] = *(const short8v*)(&As[cur][8192 + afrag_off[m]]);
#pragma unroll
    for (int n = 0; n < 4; ++n)
      bf[n] = *(const short8v*)(&Bs[cur][BS_KH + bfrag_off[n]]);
    if (st) stage_h(cur ^ 1, kks, 1);
    __builtin_amdgcn_s_barrier();
    __asm__ volatile("s_waitcnt lgkmcnt(0)" ::: "memory");
    __builtin_amdgcn_sched_barrier(0);
    __builtin_amdgcn_s_setprio(1);
#pragma unroll
    for (int mi = 0; mi < MT; ++mi)
#pragma unroll
      for (int ni = 0; ni < 4; ++ni)
        acc[mi][ni] = __builtin_amdgcn_mfma_f32_16x16x32_bf16(
            af[mi], bf[ni], acc[mi][ni], 0, 0, 0);
    __builtin_amdgcn_s_setprio(0);
    if (st) {
      WAIT_VM_H();                 // this iter's kh0 landed; kh1 flies
      __builtin_amdgcn_s_barrier();
      __builtin_amdgcn_sched_barrier(0);
    }
    cur ^= 1;
  }
#undef WAIT_VM_H

  int rowbase = row0 + wr * (MT * 16), colbase = col0 + wc * 64;
#pragma unroll
  for (int ni = 0; ni < 4; ++ni) {
    int col = colbase + ni * 16 + l15;
    float bcol = bias[col];
#pragma unroll
    for (int mi = 0; mi < MT; ++mi) {
      int rtop = rowbase + mi * 16 + lq * 4;
#pragma unroll
      for (int reg = 0; reg < 4; ++reg) {
        float vv = acc[mi][ni][reg] + bcol;
        if (RESID) vv += resid[(size_t)(rtop + reg) * nco + col];
        if (GELU) vv = 0.5f * vv * (1.f + erff(vv * 0.70710678118654752f));
        if (OUTBF16)
          ((u16*)Cv)[(size_t)(rtop + reg) * nco + col] = f2bf(vv);
        else
          ((float*)Cv)[(size_t)(rtop + reg) * nco + col] = vv;
      }
    }
  }
}

// ---------------- MFMA flash attention (packed qkv, stride 3072); out = z + attn ------
// (round-6 verified version: TLP-friendly 39KB LDS, 4 blocks/CU)
__global__ __launch_bounds__(256) void attention_kernel(
    const u16* __restrict__ qkv, const int* __restrict__ lengths,
    const float* __restrict__ zres, float* __restrict__ out) {
  const int LDQ = 3072;
  __shared__ u16 Vt[64 * VT_STRIDE];
  __shared__ u16 Pb[4][16 * 40];
  int hh = blockIdx.x & 1;
  int h = (blockIdx.x >> 1) & 15;
  int b = blockIdx.x >> 5;
  int tid = threadIdx.x;
  const size_t base = ((size_t)b * Sz) * LDQ + (size_t)h * DHEAD;
  const u16* qp = qkv + base;
  const u16* kp = qkv + base + 1024;
  const u16* vp = qkv + base + 2048;

  for (int idx = tid; idx < 256 * 16; idx += 256) {
    int key = idx >> 4, d4 = (idx & 15) * 4;
    uint2 vv;
    if (key < Sz) vv = *(const uint2*)(vp + (size_t)key * LDQ + d4);
    else { vv.x = 0u; vv.y = 0u; }
    Vt[(d4 + 0) * VT_STRIDE + key] = (u16)(vv.x & 0xFFFF);
    Vt[(d4 + 1) * VT_STRIDE + key] = (u16)(vv.x >> 16);
    Vt[(d4 + 2) * VT_STRIDE + key] = (u16)(vv.y & 0xFFFF);
    Vt[(d4 + 3) * VT_STRIDE + key] = (u16)(vv.y >> 16);
  }
  __syncthreads();

  int w = tid >> 6, lane = tid & 63;
  int qgroup = lane >> 4, qcol = lane & 15;
  int len_b = get_len(lengths, b);

  for (int qt = hh * 8 + w; qt < hh * 8 + 8 && qt < 15; qt += 4) {
    const u16* qrow = qp + (size_t)(qt * 16 + qcol) * LDQ;
    short8v aq0 = *(const short8v*)(qrow + qgroup * 8);
    short8v aq1 = *(const short8v*)(qrow + 32 + qgroup * 8);
    floatx4 o0 = {0.f, 0.f, 0.f, 0.f}, o1 = o0, o2 = o0, o3 = o0;
    float m_run[4] = {-1e30f, -1e30f, -1e30f, -1e30f};
    float l_run[4] = {0.f, 0.f, 0.f, 0.f};
    int nsteps = (qt + 2) >> 1;

    for (int st = 0; st < nsteps; ++st) {
      int t0 = 2 * st, t1 = 2 * st + 1;
      bool has1 = (t1 <= qt);
      floatx4 s0 = {0.f, 0.f, 0.f, 0.f};
      {
        const u16* kr = kp + (size_t)(t0 * 16 + qcol) * LDQ;
        short8v bk0 = *(const short8v*)(kr + qgroup * 8);
        short8v bk1 = *(const short8v*)(kr + 32 + qgroup * 8);
        s0 = __builtin_amdgcn_mfma_f32_16x16x32_bf16(aq0, bk0, s0, 0, 0, 0);
        s0 = __builtin_amdgcn_mfma_f32_16x16x32_bf16(aq1, bk1, s0, 0, 0, 0);
      }
      floatx4 s1 = {0.f, 0.f, 0.f, 0.f};
      if (has1) {
        const u16* kr = kp + (size_t)(t1 * 16 + qcol) * LDQ;
        short8v bk0 = *(const short8v*)(kr + qgroup * 8);
        short8v bk1 = *(const short8v*)(kr + 32 + qgroup * 8);
        s1 = __builtin_amdgcn_mfma_f32_16x16x32_bf16(aq0, bk0, s1, 0, 0, 0);
        s1 = __builtin_amdgcn_mfma_f32_16x16x32_bf16(aq1, bk1, s1, 0, 0, 0);
      }
      int kg0 = t0 * 16 + qcol, kg1 = t1 * 16 + qcol;
      float p0[4], p1[4];
#pragma unroll
      for (int rg = 0; rg < 4; ++rg) {
        int row_g = qt * 16 + qgroup * 4 + rg;
        float x0 = (kg0 <= row_g) ? s0[rg] * 0.03125f : -1e30f;
        float x1 = (has1 && kg1 <= row_g) ? s1[rg] * 0.03125f : -1e30f;
        float mx = fmaxf(x0, x1);
        mx = fmaxf(mx, __shfl_xor(mx, 1));
        mx = fmaxf(mx, __shfl_xor(mx, 2));
        mx = fmaxf(mx, __shfl_xor(mx, 4));
        mx = fmaxf(mx, __shfl_xor(mx, 8));
        float mnew = fmaxf(m_run[rg], mx);
        float alpha = __expf(m_run[rg] - mnew);
        float e0 = __expf(x0 - mnew);
        float e1 = __expf(x1 - mnew);
        float rs = e0 + e1;
        rs += __shfl_xor(rs, 1);
        rs += __shfl_xor(rs, 2);
        rs += __shfl_xor(rs, 4);
        rs += __shfl_xor(rs, 8);
        l_run[rg] = l_run[rg] * alpha + rs;
        m_run[rg] = mnew;
        o0[rg] *= alpha; o1[rg] *= alpha; o2[rg] *= alpha; o3[rg] *= alpha;
        p0[rg] = e0; p1[rg] = e1;
      }
#pragma unroll
      for (int rg = 0; rg < 4; ++rg) {
        int rl = qgroup * 4 + rg;
        Pb[w][rl * 40 + qcol] = f2bf(p0[rg]);
        Pb[w][rl * 40 + 16 + qcol] = f2bf(p1[rg]);
      }
      __asm__ volatile("s_waitcnt lgkmcnt(0)" ::: "memory");
      short8v pa = *(const short8v*)(&Pb[w][qcol * 40 + qgroup * 8]);
      int kb0 = st * 32 + qgroup * 8;
      short8v bv0 = *(const short8v*)(&Vt[(0 * 16 + qcol) * VT_STRIDE + kb0]);
      short8v bv1 = *(const short8v*)(&Vt[(1 * 16 + qcol) * VT_STRIDE + kb0]);
      short8v bv2 = *(const short8v*)(&Vt[(2 * 16 + qcol) * VT_STRIDE + kb0]);
      short8v bv3 = *(const short8v*)(&Vt[(3 * 16 + qcol) * VT_STRIDE + kb0]);
      o0 = __builtin_amdgcn_mfma_f32_16x16x32_bf16(pa, bv0, o0, 0, 0, 0);
      o1 = __builtin_amdgcn_mfma_f32_16x16x32_bf16(pa, bv1, o1, 0, 0, 0);
      o2 = __builtin_amdgcn_mfma_f32_16x16x32_bf16(pa, bv2, o2, 0, 0, 0);
      o3 = __builtin_amdgcn_mfma_f32_16x16x32_bf16(pa, bv3, o3, 0, 0, 0);
    }

#pragma unroll
    for (int rg = 0; rg < 4; ++rg) {
      int row_g = qt * 16 + qgroup * 4 + rg;
      float vmask = (row_g < len_b) ? (1.f / l_run[rg]) : 0.f;
      size_t ob = ((size_t)b * Sz + row_g) * Hz + (size_t)h * DHEAD + qcol;
      out[ob]      = zres[ob]      + o0[rg] * vmask;
      out[ob + 16] = zres[ob + 16] + o1[rg] * vmask;
      out[ob + 32] = zres[ob + 32] + o2[rg] * vmask;
      out[ob + 48] = zres[ob + 48] + o3[rg] * vmask;
    }
  }
}

// ---------------- LayerNorm of r (residual pre-added); writes z, z_bf ----------------
__global__ __launch_bounds__(256) void add_ln_kernel(
    float* __restrict__ z, u16* __restrict__ z_bf, const float* __restrict__ r,
    const float* __restrict__ gamma, const float* __restrict__ beta) {
  int bs = blockIdx.x, tid = threadIdx.x;
  size_t base = (size_t)bs * Hz;
  __shared__ float sred[256];
  float4 v4 = *(const float4*)(r + base + tid * 4);
  float sum = v4.x + v4.y + v4.z + v4.w;
  sred[tid] = sum; __syncthreads();
  for (int off = 128; off > 0; off >>= 1) {
    if (tid < off) sred[tid] += sred[tid + off];
    __syncthreads();
  }
  float mean = sred[0] * (1.f / Hz); __syncthreads();
  float dx = v4.x - mean, dy = v4.y - mean, dz = v4.z - mean, dw = v4.w - mean;
  sred[tid] = dx * dx + dy * dy + dz * dz + dw * dw; __syncthreads();
  for (int off = 128; off > 0; off >>= 1) {
    if (tid < off) sred[tid] += sred[tid + off];
    __syncthreads();
  }
  float rstd = rsqrtf(sred[0] * (1.f / Hz) + 1e-5f);
  float4 g4 = *(const float4*)(gamma + tid * 4);
  float4 b4 = *(const float4*)(beta + tid * 4);
  float4 o;
  o.x = dx * rstd * g4.x + b4.x;
  o.y = dy * rstd * g4.y + b4.y;
  o.z = dz * rstd * g4.z + b4.z;
  o.w = dw * rstd * g4.w + b4.w;
  *(float4*)(z + base + tid * 4) = o;
  uint2 pk;
  pk.x = (u32)f2bf(o.x) | ((u32)f2bf(o.y) << 16);
  pk.y = (u32)f2bf(o.z) | ((u32)f2bf(o.w) << 16);
  *(uint2*)(z_bf + base + tid * 4) = pk;
}

// ---------------- pool phase 1 ----------------
__global__ __launch_bounds__(256) void pool1_kernel(
    const float* __restrict__ z, float* __restrict__ pooled) {
  int chunk = blockIdx.x, b = blockIdx.y, tid = threadIdx.x;
  int h = chunk * 128 + (tid & 127);
  int half = tid >> 7;
  __shared__ float sred[256];
  const float* zp = z + ((size_t)b * Sz + half * 120) * Hz + h;
  float s = 0.f;
  for (int i = 0; i < 120; ++i) s += zp[(size_t)i * Hz];
  sred[tid] = s; __syncthreads();
  if (tid < 128)
    pooled[(size_t)b * Hz + chunk * 128 + tid] =
        (sred[tid] + sred[tid + 128]) * (1.f / Sz);
}

// ---------------- pool phase 2: FC + softmax -> fp32 out ----------------
__global__ __launch_bounds__(256) void pool2_kernel(
    const float* __restrict__ pooled, const float* __restrict__ Wfc,
    const float* __restrict__ bfc, float* __restrict__ out) {
  int b = blockIdx.x, tid = threadIdx.x;
  __shared__ float red[256][4];
  float acc[4] = {0.f, 0.f, 0.f, 0.f};
#pragma unroll
  for (int j = 0; j < 4; ++j) {
    int hh = tid * 4 + j;
    float z2 = pooled[(size_t)b * Hz + hh];
#pragma unroll
    for (int c = 0; c < 4; ++c) acc[c] += z2 * Wfc[hh * 4 + c];
  }
#pragma unroll
  for (int c = 0; c < 4; ++c) red[tid][c] = acc[c];
  __syncthreads();
  for (int off = 128; off > 0; off >>= 1) {
    if (tid < off)
#pragma unroll
      for (int c = 0; c < 4; ++c) red[tid][c] += red[tid + off][c];
    __syncthreads();
  }
  if (tid == 0) {
    float lg[4], m = -1e30f;
#pragma unroll
    for (int c = 0; c < 4; ++c) { lg[c] = red[0][c] + bfc[c]; m = fmaxf(m, lg[c]); }
    float s = 0.f;
#pragma unroll
    for (int c = 0; c < 4; ++c) { lg[c] = expf(lg[c] - m); s += lg[c]; }
    float inv = 1.f / s;
#pragma unroll
    for (int c = 0; c < 4; ++c) out[b * 4 + c] = lg[c] * inv;
  }
}

extern "C" void kernel_launch(void* const* d_in, const int* in_sizes, int n_in,
                              void* d_out, int out_size, void* d_ws, size_t ws_size,
                              hipStream_t stream) {
  const float* x     = (const float*)d_in[0];
  const float* w_emb = (const float*)d_in[1];
  const float* p_emb = (const float*)d_in[2];
  const float* Wq = (const float*)d_in[3];
  const float* bq = (const float*)d_in[4];
  const float* Wk = (const float*)d_in[5];
  const float* bk = (const float*)d_in[6];
  const float* Wv = (const float*)d_in[7];
  const float* bv = (const float*)d_in[8];
  const float* W1 = (const float*)d_in[9];
  const float* b1 = (const float*)d_in[10];
  const float* W2 = (const float*)d_in[11];
  const float* b2 = (const float*)d_in[12];
  const float* ln1s = (const float*)d_in[13];
  const float* ln1b = (const float*)d_in[14];
  const float* ln2s = (const float*)d_in[15];
  const float* ln2b = (const float*)d_in[16];
  const float* Wfc  = (const float*)d_in[17];
  const float* bfc  = (const float*)d_in[18];
  const int* lengths = (const int*)d_in[19];
  float* out = (float*)d_out;

  const size_t BSH = (size_t)Bz * Sz * Hz;   // 7,864,320
  float* z    = (float*)d_ws;                // fp32 BSH
  float* ao   = z + BSH;                     // fp32 BSH (z+attn / z1+ff2)
  u16* z_bf   = (u16*)(ao + BSH);            // bf16 BSH
  u16* ffb    = z_bf + BSH;                  // bf16 BSH (FF1 out)
  u16* qkv    = ffb + BSH;                   // bf16 3*BSH
  u16* wt     = qkv + 3 * BSH;               // bf16 5M
  float* bqkv = (float*)(wt + 5 * 1024 * 1024);   // Lz*3072
  float* pooled = bqkv + Lz * 3072;          // 32*1024 fp32

  embed_kernel<<<Bz * Sz, 256, 0, stream>>>(x, w_emb, p_emb, lengths, z, z_bf);
  bias_concat<<<Lz * 3072 / 256, 256, 0, stream>>>(bq, bk, bv, bqkv);

  for (int i = 0; i < Lz; ++i) {
    size_t wo = (size_t)i * Hz * Hz, bo = (size_t)i * Hz;
    WconvArgs wa;
    wa.src[0] = Wq + wo; wa.src[1] = Wk + wo; wa.src[2] = Wv + wo;
    wa.src[3] = W1 + wo; wa.src[4] = W2 + wo;
    wa.dst[0] = wt;                     wa.dst[1] = wt + 1024 * 1024;
    wa.dst[2] = wt + 2 * 1024 * 1024;   wa.dst[3] = wt + 3 * 1024 * 1024;
    wa.dst[4] = wt + 4 * 1024 * 1024;
    wconv5<<<dim3(32, 32, 5), 256, 0, stream>>>(wa);

    gemm_mfma<256, true, false, false><<<30 * 12, 512, 0, stream>>>(
        z_bf, wt, bqkv + (size_t)i * 3072, nullptr, qkv, 3072);
    attention_kernel<<<Bz * NHEADS * 2, 256, 0, stream>>>(qkv, lengths, z, ao);
    add_ln_kernel<<<Bz * Sz, 256, 0, stream>>>(z, z_bf, ao, ln1s + bo, ln1b + bo);
    gemm_mfma<128, true, true, false><<<30 * 8, 512, 0, stream>>>(
        z_bf, wt + 3 * 1024 * 1024, b1 + bo, nullptr, ffb, 1024);
    gemm_mfma<128, false, false, true><<<30 * 8, 512, 0, stream>>>(
        ffb, wt + 4 * 1024 * 1024, b2 + bo, z, ao, 1024);
    add_ln_kernel<<<Bz * Sz, 256, 0, stream>>>(z, z_bf, ao, ln2s + bo, ln2b + bo);
  }
  pool1_kernel<<<dim3(8, Bz), 256, 0, stream>>>(z, pooled);
  pool2_kernel<<<Bz, 256, 0, stream>>>(pooled, Wfc, bfc, out);
}